// Round 3
// baseline (803.211 us; speedup 1.0000x reference)
//
#include <hip/hip_runtime.h>
#include <math.h>

// Problem constants (reference: x[8,2048,1024] f32, W[1024,64] f32)
#define BB 8
#define NN 2048
#define DD 1024
#define EE 64
#define CAP 64
#define NTOK (BB * NN)          // 16384
#define OUT_T_FLOATS 67108864   // 8*2048*64*64 per tensor
#define OUT_T_F4     16777216   // float4 count per tensor

typedef float vfloat4 __attribute__((ext_vector_type(4)));  // nontemporal-compatible

// Workspace layout (bytes):
//   recs      float4[NTOK]   @ 0        {g1n, g2n, bits(i1), bits(i2 | flag<<8)}
//   frecs     float4[NTOK]   @ 262144   {g1|0, g2|0, bits(e1*64+p1 | -1), bits(e2*64+p2 | -1)}
//   dens      float[512*64]  @ 524288   per-block density partial sums
//   lossp     float[8]       @ 655360   per-batch loss partials

// ---------------------------------------------------------------------------
// Kernel G: logits GEMM + softmax + top2 + gates + density partials.
// Block = 256 (4 waves); wave handles 8 tokens, lane j owns expert j.
// x read as float4: 4 FMAs per load on both the scalar-load path
// (s_load_dwordx4 if uniformity inference fires) and the broadcast path.
// ---------------------------------------------------------------------------
__global__ __launch_bounds__(256) void gating_kernel(
    const float* __restrict__ x, const float* __restrict__ W,
    float4* __restrict__ recs, float* __restrict__ dens)
{
    __shared__ float Wl[64 * 64];     // 16 KB
    __shared__ float dred[4][64];

    const int lane = threadIdx.x & 63;
    const int wave = __builtin_amdgcn_readfirstlane(threadIdx.x >> 6);
    const int tok0 = blockIdx.x * 32 + wave * 8;

    float acc[8];
#pragma unroll
    for (int t = 0; t < 8; ++t) acc[t] = 0.f;

    for (int dc = 0; dc < 16; ++dc) {
        __syncthreads();
        {   // stage W rows [dc*64, dc*64+64): 4096 floats, coalesced float4
            const float4* wg = (const float4*)(W + dc * 64 * 64);
            float4* wl = (float4*)Wl;
#pragma unroll
            for (int k = 0; k < 4; ++k)
                wl[threadIdx.x + 256 * k] = wg[threadIdx.x + 256 * k];
        }
        __syncthreads();
        // x chunk base for this wave's 8 tokens; float4 row stride = 256
        const float4* xc4 = (const float4*)(x + (size_t)tok0 * DD + dc * 64);
#pragma unroll 2
        for (int q = 0; q < 16; ++q) {
            const float w0 = Wl[(q * 4 + 0) * 64 + lane];  // lane-stride 1: conflict-free
            const float w1 = Wl[(q * 4 + 1) * 64 + lane];
            const float w2 = Wl[(q * 4 + 2) * 64 + lane];
            const float w3 = Wl[(q * 4 + 3) * 64 + lane];
#pragma unroll
            for (int t = 0; t < 8; ++t) {
                const float4 xv = xc4[t * 256 + q];  // wave-uniform address
                acc[t] = fmaf(xv.x, w0, acc[t]);     // same add order as R1 (dd asc)
                acc[t] = fmaf(xv.y, w1, acc[t]);
                acc[t] = fmaf(xv.z, w2, acc[t]);
                acc[t] = fmaf(xv.w, w3, acc[t]);
            }
        }
    }

    float densacc = 0.f;
#pragma unroll 1
    for (int t = 0; t < 8; ++t) {
        const float lv = acc[t];
        // argmax: value desc, index asc on ties (matches jnp.argmax)
        float v = lv; int bi = lane;
#pragma unroll
        for (int off = 32; off; off >>= 1) {
            float ov = __shfl_xor(v, off);
            int   oi = __shfl_xor(bi, off);
            if (ov > v || (ov == v && oi < bi)) { v = ov; bi = oi; }
        }
        const float m1 = v; const int i1 = bi;
        float v2 = (lane == i1) ? -INFINITY : lv; int b2 = lane;
#pragma unroll
        for (int off = 32; off; off >>= 1) {
            float ov = __shfl_xor(v2, off);
            int   oi = __shfl_xor(b2, off);
            if (ov > v2 || (ov == v2 && oi < b2)) { v2 = ov; b2 = oi; }
        }
        const float m2 = v2; const int i2 = b2;

        float ex = expf(lv - m1);
        float Z = ex;
#pragma unroll
        for (int off = 32; off; off >>= 1) Z += __shfl_xor(Z, off);
        float g1 = 1.0f / Z;               // p[i1]
        float g2 = expf(m2 - m1) * g1;     // p[i2]
        float den = g1 + g2 + 1e-9f;
        float g1n = g1 / den;
        float g2n = g2 / den;
        int flag = (g2n > 0.2f) ? 1 : 0;   // threshold on normalized gate_2

        densacc += ex * g1;                // p_t[lane] for density proxy

        if (lane == 0)
            recs[tok0 + t] = make_float4(g1n, g2n, __int_as_float(i1),
                                         __int_as_float(i2 | (flag << 8)));
    }

    dred[wave][lane] = densacc;
    __syncthreads();
    if (wave == 0) {
        float s = dred[0][lane] + dred[1][lane] + dred[2][lane] + dred[3][lane];
        dens[blockIdx.x * 64 + lane] = s;  // per-block partial, no atomics
    }
}

// ---------------------------------------------------------------------------
// Kernel S: ballot-based parallel rank for position-in-expert.
// 1 block/batch, 1024 threads = 16 waves; lane = token-within-group-of-64.
// Per 64-token group: 6 ballots of expert-index bits give (a) each token's
// rank among same-expert tokens before it (popc(match & below)) and (b) the
// per-expert histogram (popc(match_v), lane v = expert). Cross-group
// exclusive prefix over the 32 groups by wave 0 (lane = expert).
// ---------------------------------------------------------------------------
__global__ __launch_bounds__(1024) void scan_kernel(
    const float4* __restrict__ recs, const float* __restrict__ dens,
    float4* __restrict__ frecs, float* __restrict__ lossp)
{
    const int b = blockIdx.x;
    __shared__ int hist1[32][64], pre1[32][64];
    __shared__ int hist2[32][64], pre2[32][64];
    __shared__ int base2[64];
    __shared__ float dsum[64];

    const int tid = threadIdx.x;
    const int lane = tid & 63;
    const int wave = tid >> 6;

    float4 r[2];
    int e1[2], e2[2], fl[2], rank1[2], rank2[2];
    const unsigned long long below = (1ull << lane) - 1ull;

#pragma unroll
    for (int u = 0; u < 2; ++u) {
        const int g = 2 * wave + u;
        const int tok = g * 64 + lane;
        float4 rr = recs[b * NN + tok];
        r[u] = rr;
        e1[u] = __float_as_int(rr.z);
        int i2f = __float_as_int(rr.w);
        e2[u] = i2f & 63;
        fl[u] = i2f >> 8;

        // pass 1: top-1 expert
        unsigned long long m = ~0ull, mv = ~0ull;
#pragma unroll
        for (int bit = 0; bit < 6; ++bit) {
            unsigned long long vt = __ballot((e1[u] >> bit) & 1);
            m  &= ((e1[u] >> bit) & 1) ? vt : ~vt;
            mv &= ((lane  >> bit) & 1) ? vt : ~vt;
        }
        rank1[u] = __popcll(m & below);
        hist1[g][lane] = __popcll(mv);

        // pass 2: top-2 expert, only threshold-passing tokens count
        unsigned long long fv = __ballot(fl[u]);
        m = fv; mv = fv;
#pragma unroll
        for (int bit = 0; bit < 6; ++bit) {
            unsigned long long vt = __ballot((e2[u] >> bit) & 1);
            m  &= ((e2[u] >> bit) & 1) ? vt : ~vt;
            mv &= ((lane  >> bit) & 1) ? vt : ~vt;
        }
        rank2[u] = __popcll(m & below);
        hist2[g][lane] = __popcll(mv);
    }

    if (wave == 0) {  // density sums for this batch (uncapped proxy)
        float s = 0.f;
        for (int k = 0; k < 64; ++k) s += dens[(b * 64 + k) * 64 + lane];
        dsum[lane] = s;
    }
    __syncthreads();

    if (wave == 0) {  // cross-group exclusive prefix, lane = expert
        int run = 0;
#pragma unroll
        for (int g = 0; g < 32; ++g) { pre1[g][lane] = run; run += hist1[g][lane]; }
        base2[lane] = run < CAP ? run : CAP;     // mask_1_count = min(count, cap)
        int run2 = 0;
#pragma unroll
        for (int g = 0; g < 32; ++g) { pre2[g][lane] = run2; run2 += hist2[g][lane]; }
        // loss partial: sum_e dsum[e] * UNCAPPED count_e
        float v = dsum[lane] * (float)run;
#pragma unroll
        for (int off = 32; off; off >>= 1) v += __shfl_xor(v, off);
        if (lane == 0) lossp[b] = v;
    }
    __syncthreads();

#pragma unroll
    for (int u = 0; u < 2; ++u) {
        const int g = 2 * wave + u;
        const int tok = g * 64 + lane;
        int p1 = rank1[u] + pre1[g][e1[u]];
        int k1 = p1 < CAP;
        int p2 = rank2[u] + pre2[g][e2[u]] + base2[e2[u]];
        int k2 = fl[u] && (p2 < CAP);
        float4 fr;
        fr.x = k1 ? r[u].x : 0.f;
        fr.y = k2 ? r[u].y : 0.f;
        fr.z = __int_as_float(k1 ? (e1[u] * CAP + p1) : -1);
        fr.w = __int_as_float(k2 ? (e2[u] * CAP + p2) : -1);
        frecs[b * NN + tok] = fr;
    }
}

// ---------------------------------------------------------------------------
// Kernel F: write all 537 MB of dispatch+combine, nontemporal (write-once
// data -- skip L2). Thread owns 8 floats (2 float4) of each tensor.
// ---------------------------------------------------------------------------
__global__ __launch_bounds__(256) void fill_kernel(
    const float4* __restrict__ frecs, const float* __restrict__ lossp,
    float* __restrict__ out)
{
    const int tid = blockIdx.x * 256 + threadIdx.x;   // 0 .. 8388607
    const int token = tid >> 9;          // 512 threads per token slab
    const int e  = (tid >> 3) & 63;
    const int c8 = tid & 7;              // which 8-wide capacity chunk
    const float4 r = frecs[token];       // broadcast: L2 hit

    const int p1 = __float_as_int(r.z);  // e1*64+pos1 or -1
    const int p2 = __float_as_int(r.w);  // e2*64+pos2 or -1
    const int s0 = e * 64 + c8 * 8;      // slot id of element j=0

    float dv[8], cv[8];
#pragma unroll
    for (int j = 0; j < 8; ++j) {
        const int s = s0 + j;
        const bool h1 = (p1 == s);
        const bool h2 = (p2 == s);
        dv[j] = (h1 | h2) ? 1.f : 0.f;
        cv[j] = h1 ? r.x : (h2 ? r.y : 0.f);
    }

    vfloat4* o4 = (vfloat4*)out;
    const size_t o = (size_t)tid * 2;
    vfloat4 d0 = {dv[0], dv[1], dv[2], dv[3]};
    vfloat4 d1 = {dv[4], dv[5], dv[6], dv[7]};
    vfloat4 c0 = {cv[0], cv[1], cv[2], cv[3]};
    vfloat4 c1 = {cv[4], cv[5], cv[6], cv[7]};
    __builtin_nontemporal_store(d0, o4 + o);
    __builtin_nontemporal_store(d1, o4 + o + 1);
    __builtin_nontemporal_store(c0, o4 + OUT_T_F4 + o);
    __builtin_nontemporal_store(c1, o4 + OUT_T_F4 + o + 1);

    if (tid == 0) {
        float s = 0.f;
        for (int k = 0; k < 8; ++k) s += lossp[k];
        // loss = sum_{b,e}(dsum_e * count_e) * e^2 / (b*e*n^2) = s / 524288
        out[2 * OUT_T_FLOATS] = s * (1.0f / 524288.0f);
    }
}

extern "C" void kernel_launch(void* const* d_in, const int* in_sizes, int n_in,
                              void* d_out, int out_size, void* d_ws, size_t ws_size,
                              hipStream_t stream)
{
    const float* x = (const float*)d_in[0];
    const float* W = (const float*)d_in[1];
    float* out = (float*)d_out;
    char* ws = (char*)d_ws;

    float4* recs  = (float4*)(ws);
    float4* frecs = (float4*)(ws + 262144);
    float*  dens  = (float*)(ws + 524288);
    float*  lossp = (float*)(ws + 655360);

    gating_kernel<<<512, 256, 0, stream>>>(x, W, recs, dens);
    scan_kernel<<<8, 1024, 0, stream>>>(recs, dens, frecs, lossp);
    fill_kernel<<<32768, 256, 0, stream>>>(frecs, lossp, out);
}

// Round 4
// 741.860 us; speedup vs baseline: 1.0827x; 1.0827x over previous
//
#include <hip/hip_runtime.h>
#include <math.h>

// Problem constants (reference: x[8,2048,1024] f32, W[1024,64] f32)
#define BB 8
#define NN 2048
#define DD 1024
#define EE 64
#define CAP 64
#define NTOK (BB * NN)          // 16384
#define OUT_T_FLOATS 67108864   // 8*2048*64*64 per tensor
#define OUT_T_F4     16777216   // float4 count per tensor

typedef float vfloat4 __attribute__((ext_vector_type(4)));

// Workspace layout (bytes):
//   recs      float4[NTOK]   @ 0        {g1n, g2n, bits(i1), bits(i2 | flag<<8)}
//   frecs     float4[NTOK]   @ 262144   {g1|0, g2|0, bits(e1*64+p1 | -1), bits(e2*64+p2 | -1)}
//   dens      float[256*64]  @ 524288   per-gating-block density partials
//   lossp     float[8]       @ 589824   per-batch loss partials

// ---------------------------------------------------------------------------
// Kernel G (v2): lane = token, thread computes ALL 64 experts.
// 256 blocks x 256 threads; block owns 64 tokens; wave w covers k-quarter
// [256w, 256w+256). x values are lane-local VGPRs (no broadcast needed);
// W row addresses are fully wave-uniform -> s_load, FMA reads W from SGPR.
// Partials reduced through LDS, then R1's shuffle epilogue (lane = expert).
// ---------------------------------------------------------------------------
__global__ __launch_bounds__(256) void gating_kernel(
    const float* __restrict__ x, const float* __restrict__ W,
    float4* __restrict__ recs, float* __restrict__ dens)
{
    __shared__ float part[4][64][68];   // [k-quarter][token][expert(+pad)] ~69.6 KB
    __shared__ float dred[4][64];

    const int lane = threadIdx.x & 63;
    const int wave = __builtin_amdgcn_readfirstlane(threadIdx.x >> 6);
    const int tok  = blockIdx.x * 64 + lane;       // this lane's token (GEMM phase)

    float acc[64];
#pragma unroll
    for (int e = 0; e < 64; ++e) acc[e] = 0.f;

    // ---- GEMM phase: acc[e] += x[tok][k] * W[k][e], k in this wave's quarter
    const float4* xq = (const float4*)(x + (size_t)tok * DD + wave * 256);
    const float*  wq = W + (size_t)(wave * 256) * EE;   // wave-uniform

    float4 xb[2][4];
#pragma unroll
    for (int j = 0; j < 4; ++j) xb[0][j] = xq[j];       // first 16-k chunk

#pragma unroll 1
    for (int c = 0; c < 16; ++c) {                      // 16 chunks x 16 k
        const int cur = c & 1;
        if (c < 15) {
#pragma unroll
            for (int j = 0; j < 4; ++j) xb[cur ^ 1][j] = xq[(c + 1) * 4 + j];
        }
        const float* wr = wq + c * 16 * EE;             // uniform
#pragma unroll
        for (int j = 0; j < 4; ++j) {
            const float4 xv = xb[cur][j];
#pragma unroll
            for (int kk = 0; kk < 4; ++kk) {
                const float xs = (kk == 0) ? xv.x : (kk == 1) ? xv.y
                               : (kk == 2) ? xv.z : xv.w;
                const float* wk = wr + (j * 4 + kk) * EE;   // uniform -> s_load
#pragma unroll
                for (int e = 0; e < 64; e += 4) {
                    const float4 wv = *(const float4*)(wk + e);
                    acc[e + 0] = fmaf(xs, wv.x, acc[e + 0]);
                    acc[e + 1] = fmaf(xs, wv.y, acc[e + 1]);
                    acc[e + 2] = fmaf(xs, wv.z, acc[e + 2]);
                    acc[e + 3] = fmaf(xs, wv.w, acc[e + 3]);
                }
            }
        }
    }

    // ---- reduce partials through LDS
#pragma unroll
    for (int e = 0; e < 64; e += 4)
        *(float4*)&part[wave][lane][e] =
            make_float4(acc[e], acc[e + 1], acc[e + 2], acc[e + 3]);
    __syncthreads();

    // ---- epilogue: wave w handles tokens [16w, 16w+16); lane = expert
    const int t0 = wave * 16;
    float densacc = 0.f;
#pragma unroll 1
    for (int ti = 0; ti < 16; ++ti) {
        const int t = t0 + ti;
        const float lv = ((part[0][t][lane] + part[1][t][lane])
                        + part[2][t][lane]) + part[3][t][lane];

        // argmax: value desc, index asc on ties (matches jnp.argmax)
        float v = lv; int bi = lane;
#pragma unroll
        for (int off = 32; off; off >>= 1) {
            float ov = __shfl_xor(v, off);
            int   oi = __shfl_xor(bi, off);
            if (ov > v || (ov == v && oi < bi)) { v = ov; bi = oi; }
        }
        const float m1 = v; const int i1 = bi;
        float v2 = (lane == i1) ? -INFINITY : lv; int b2 = lane;
#pragma unroll
        for (int off = 32; off; off >>= 1) {
            float ov = __shfl_xor(v2, off);
            int   oi = __shfl_xor(b2, off);
            if (ov > v2 || (ov == v2 && oi < b2)) { v2 = ov; b2 = oi; }
        }
        const float m2 = v2; const int i2 = b2;

        float ex = expf(lv - m1);
        float Z = ex;
#pragma unroll
        for (int off = 32; off; off >>= 1) Z += __shfl_xor(Z, off);
        float g1 = 1.0f / Z;               // p[i1]
        float g2 = expf(m2 - m1) * g1;     // p[i2]
        float den = g1 + g2 + 1e-9f;
        float g1n = g1 / den;
        float g2n = g2 / den;
        int flag = (g2n > 0.2f) ? 1 : 0;   // threshold on NORMALIZED gate_2

        densacc += ex * g1;                // p_t[lane] for density proxy

        if (lane == 0)
            recs[blockIdx.x * 64 + t] =
                make_float4(g1n, g2n, __int_as_float(i1),
                            __int_as_float(i2 | (flag << 8)));
    }

    dred[wave][lane] = densacc;
    __syncthreads();
    if (wave == 0) {
        float s = dred[0][lane] + dred[1][lane] + dred[2][lane] + dred[3][lane];
        dens[blockIdx.x * 64 + lane] = s;  // per-block partial, no atomics
    }
}

// ---------------------------------------------------------------------------
// Kernel S: ballot-based parallel rank for position-in-expert.
// 1 block/batch, 1024 threads = 16 waves; lane = token-within-group-of-64.
// ---------------------------------------------------------------------------
__global__ __launch_bounds__(1024) void scan_kernel(
    const float4* __restrict__ recs, const float* __restrict__ dens,
    float4* __restrict__ frecs, float* __restrict__ lossp)
{
    const int b = blockIdx.x;
    __shared__ int hist1[32][64], pre1[32][64];
    __shared__ int hist2[32][64], pre2[32][64];
    __shared__ int base2[64];
    __shared__ float dsum[64];

    const int tid = threadIdx.x;
    const int lane = tid & 63;
    const int wave = tid >> 6;

    float4 r[2];
    int e1[2], e2[2], fl[2], rank1[2], rank2[2];
    const unsigned long long below = (1ull << lane) - 1ull;

#pragma unroll
    for (int u = 0; u < 2; ++u) {
        const int g = 2 * wave + u;
        const int tok = g * 64 + lane;
        float4 rr = recs[b * NN + tok];
        r[u] = rr;
        e1[u] = __float_as_int(rr.z);
        int i2f = __float_as_int(rr.w);
        e2[u] = i2f & 63;
        fl[u] = i2f >> 8;

        unsigned long long m = ~0ull, mv = ~0ull;
#pragma unroll
        for (int bit = 0; bit < 6; ++bit) {
            unsigned long long vt = __ballot((e1[u] >> bit) & 1);
            m  &= ((e1[u] >> bit) & 1) ? vt : ~vt;
            mv &= ((lane  >> bit) & 1) ? vt : ~vt;
        }
        rank1[u] = __popcll(m & below);
        hist1[g][lane] = __popcll(mv);

        unsigned long long fv = __ballot(fl[u]);
        m = fv; mv = fv;
#pragma unroll
        for (int bit = 0; bit < 6; ++bit) {
            unsigned long long vt = __ballot((e2[u] >> bit) & 1);
            m  &= ((e2[u] >> bit) & 1) ? vt : ~vt;
            mv &= ((lane  >> bit) & 1) ? vt : ~vt;
        }
        rank2[u] = __popcll(m & below);
        hist2[g][lane] = __popcll(mv);
    }

    if (wave == 0) {  // density sums: 32 gating blocks per batch now
        float s = 0.f;
        for (int k = 0; k < 32; ++k) s += dens[(b * 32 + k) * 64 + lane];
        dsum[lane] = s;
    }
    __syncthreads();

    if (wave == 0) {  // cross-group exclusive prefix, lane = expert
        int run = 0;
#pragma unroll
        for (int g = 0; g < 32; ++g) { pre1[g][lane] = run; run += hist1[g][lane]; }
        base2[lane] = run < CAP ? run : CAP;     // mask_1_count = min(count, cap)
        int run2 = 0;
#pragma unroll
        for (int g = 0; g < 32; ++g) { pre2[g][lane] = run2; run2 += hist2[g][lane]; }
        float v = dsum[lane] * (float)run;       // UNCAPPED count for loss
#pragma unroll
        for (int off = 32; off; off >>= 1) v += __shfl_xor(v, off);
        if (lane == 0) lossp[b] = v;
    }
    __syncthreads();

#pragma unroll
    for (int u = 0; u < 2; ++u) {
        const int g = 2 * wave + u;
        const int tok = g * 64 + lane;
        int p1 = rank1[u] + pre1[g][e1[u]];
        int k1 = p1 < CAP;
        int p2 = rank2[u] + pre2[g][e2[u]] + base2[e2[u]];
        int k2 = fl[u] && (p2 < CAP);
        float4 fr;
        fr.x = k1 ? r[u].x : 0.f;
        fr.y = k2 ? r[u].y : 0.f;
        fr.z = __int_as_float(k1 ? (e1[u] * CAP + p1) : -1);
        fr.w = __int_as_float(k2 ? (e2[u] * CAP + p2) : -1);
        frecs[b * NN + tok] = fr;
    }
}

// ---------------------------------------------------------------------------
// Kernel F (v3): block = token (16384 blocks x 256). Wave q writes quarter q
// of the token's 1024-float4 slab; each store instruction is 64 lanes x 16 B
// = 1 KB fully contiguous. Regular stores (memset-proven 6.3 TB/s path).
// One frecs read per thread (uniform within block -> scalar load).
// ---------------------------------------------------------------------------
__global__ __launch_bounds__(256) void fill_kernel(
    const float4* __restrict__ frecs, const float* __restrict__ lossp,
    float* __restrict__ out)
{
    const int token = blockIdx.x;
    const int lane = threadIdx.x & 63;
    const int wave = threadIdx.x >> 6;

    const float4 r = frecs[token];       // block-uniform
    const int p1 = __float_as_int(r.z);  // e1*64+pos1 or -1
    const int p2 = __float_as_int(r.w);  // e2*64+pos2 or -1
    const int f1 = p1 >> 2;              // -1 stays -1
    const int f2 = p2 >> 2;
    const int c1 = p1 & 3, c2 = p2 & 3;

    vfloat4* o4 = (vfloat4*)out;
    const size_t slab = (size_t)token << 10;

#pragma unroll
    for (int j = 0; j < 4; ++j) {
        const int f4 = wave * 256 + j * 64 + lane;   // float4 idx within slab
        vfloat4 d = {0.f, 0.f, 0.f, 0.f};
        vfloat4 cv = {0.f, 0.f, 0.f, 0.f};
        const bool h1 = (f1 == f4);
        const bool h2 = (f2 == f4);
#pragma unroll
        for (int jj = 0; jj < 4; ++jj) {
            const bool a1 = h1 && (c1 == jj);
            const bool a2 = h2 && (c2 == jj);
            d[jj]  = (a1 | a2) ? 1.f : 0.f;
            cv[jj] = a1 ? r.x : (a2 ? r.y : 0.f);
        }
        o4[slab + f4] = d;                           // dispatch
        o4[OUT_T_F4 + slab + f4] = cv;               // combine
    }

    if (token == 0 && threadIdx.x == 0) {
        float s = 0.f;
        for (int k = 0; k < 8; ++k) s += lossp[k];
        // loss = sum_b lossp[b] * e^2 / (b*e*n^2) = s / 524288
        out[2 * (size_t)OUT_T_FLOATS] = s * (1.0f / 524288.0f);
    }
}

extern "C" void kernel_launch(void* const* d_in, const int* in_sizes, int n_in,
                              void* d_out, int out_size, void* d_ws, size_t ws_size,
                              hipStream_t stream)
{
    const float* x = (const float*)d_in[0];
    const float* W = (const float*)d_in[1];
    float* out = (float*)d_out;
    char* ws = (char*)d_ws;

    float4* recs  = (float4*)(ws);
    float4* frecs = (float4*)(ws + 262144);
    float*  dens  = (float*)(ws + 524288);
    float*  lossp = (float*)(ws + 589824);

    gating_kernel<<<256, 256, 0, stream>>>(x, W, recs, dens);
    scan_kernel<<<8, 1024, 0, stream>>>(recs, dens, frecs, lossp);
    fill_kernel<<<16384, 256, 0, stream>>>(frecs, lossp, out);
}

// Round 5
// 730.689 us; speedup vs baseline: 1.0993x; 1.0153x over previous
//
#include <hip/hip_runtime.h>
#include <math.h>

// Problem constants (reference: x[8,2048,1024] f32, W[1024,64] f32)
#define BB 8
#define NN 2048
#define DD 1024
#define EE 64
#define CAP 64
#define NTOK (BB * NN)          // 16384
#define OUT_T_FLOATS 67108864   // 8*2048*64*64 per tensor
#define OUT_T_F4     16777216   // float4 count per tensor

typedef float vfloat4 __attribute__((ext_vector_type(4)));

// Workspace layout (bytes):
//   recs      float4[NTOK]   @ 0        {g1n, g2n, bits(i1), bits(i2 | flag<<8)}
//   frecs     float4[NTOK]   @ 262144   {g1|0, g2|0, bits(e1*64+p1 | -1), bits(e2*64+p2 | -1)}
//   dens      float[256*64]  @ 524288   per-gating-block density partials
//   lossp     float[8]       @ 589824   per-batch loss partials

// ---------------------------------------------------------------------------
// Kernel G (v3): 256 blocks x 1024 threads (16 waves = 4 waves/SIMD).
// Block owns 64 tokens; lane = token, wave = k-slice (64 k each).
// x values lane-local (no broadcast); W row addresses wave-uniform.
// Cross-slice reduction: 8 deterministic LDS rounds of 8 experts.
// vs R4: 4x more waves/SIMD (latency hiding), 4x less FMA per thread.
// ---------------------------------------------------------------------------
__global__ __launch_bounds__(1024, 4) void gating_kernel(
    const float* __restrict__ x, const float* __restrict__ W,
    float4* __restrict__ recs, float* __restrict__ dens)
{
    __shared__ float red[64][16][9];    // [token][kslice][e-sub(8)+pad] 36.9 KB
    __shared__ float logits[64][65];    // stride 65: col-write conflict-free, 16.6 KB
    __shared__ float dred[4][64];

    const int tid  = threadIdx.x;
    const int lane = tid & 63;                                   // token-in-block
    const int wave = __builtin_amdgcn_readfirstlane(tid >> 6);   // k-slice
    const int tok  = blockIdx.x * 64 + lane;

    float acc[64];
#pragma unroll
    for (int e = 0; e < 64; ++e) acc[e] = 0.f;

    const float4* xq = (const float4*)(x + (size_t)tok * DD + wave * 64);
    const float*  wq = W + (size_t)(wave * 64) * EE;             // wave-uniform

#pragma unroll 1
    for (int c = 0; c < 8; ++c) {               // 8 chunks x 8 k = 64 k
        const float4 xa = xq[c * 2];
        const float4 xb = xq[c * 2 + 1];
        const float xs[8] = {xa.x, xa.y, xa.z, xa.w, xb.x, xb.y, xb.z, xb.w};
#pragma unroll
        for (int kk = 0; kk < 8; ++kk) {
            const float4* wr = (const float4*)(wq + (c * 8 + kk) * EE); // uniform
#pragma unroll
            for (int e4 = 0; e4 < 16; ++e4) {
                const float4 wv = wr[e4];
                acc[e4 * 4 + 0] = fmaf(xs[kk], wv.x, acc[e4 * 4 + 0]);
                acc[e4 * 4 + 1] = fmaf(xs[kk], wv.y, acc[e4 * 4 + 1]);
                acc[e4 * 4 + 2] = fmaf(xs[kk], wv.z, acc[e4 * 4 + 2]);
                acc[e4 * 4 + 3] = fmaf(xs[kk], wv.w, acc[e4 * 4 + 3]);
            }
        }
    }

    // ---- deterministic cross-slice reduce: 8 rounds of 8 experts
#pragma unroll 1
    for (int g = 0; g < 8; ++g) {
#pragma unroll
        for (int j = 0; j < 8; ++j)
            red[lane][wave][j] = acc[g * 8 + j];   // lane stride 144 w: 2-way, free
        __syncthreads();
        if (tid < 512) {
            const int t = tid & 63, j = tid >> 6;  // (token, expert-sub)
            float s = 0.f;
#pragma unroll
            for (int w16 = 0; w16 < 16; ++w16) s += red[t][w16][j];  // fixed w: lanes 2-way
            logits[t][g * 8 + j] = s;              // lane stride 65 w: conflict-free
        }
        __syncthreads();
    }

    // ---- epilogue: waves 0-3, wave w handles tokens [16w,16w+16); lane = expert
    if (wave < 4) {
        const int t0 = wave * 16;
        float densacc = 0.f;
#pragma unroll 1
        for (int ti = 0; ti < 16; ++ti) {
            const int t = t0 + ti;
            const float lv = logits[t][lane];

            // argmax: value desc, index asc on ties (matches jnp.argmax)
            float v = lv; int bi = lane;
#pragma unroll
            for (int off = 32; off; off >>= 1) {
                float ov = __shfl_xor(v, off);
                int   oi = __shfl_xor(bi, off);
                if (ov > v || (ov == v && oi < bi)) { v = ov; bi = oi; }
            }
            const float m1 = v; const int i1 = bi;
            float v2 = (lane == i1) ? -INFINITY : lv; int b2 = lane;
#pragma unroll
            for (int off = 32; off; off >>= 1) {
                float ov = __shfl_xor(v2, off);
                int   oi = __shfl_xor(b2, off);
                if (ov > v2 || (ov == v2 && oi < b2)) { v2 = ov; b2 = oi; }
            }
            const float m2 = v2; const int i2 = b2;

            float ex = expf(lv - m1);
            float Z = ex;
#pragma unroll
            for (int off = 32; off; off >>= 1) Z += __shfl_xor(Z, off);
            float g1 = 1.0f / Z;               // p[i1]
            float g2 = expf(m2 - m1) * g1;     // p[i2]
            float den = g1 + g2 + 1e-9f;
            float g1n = g1 / den;
            float g2n = g2 / den;
            int flag = (g2n > 0.2f) ? 1 : 0;   // threshold on NORMALIZED gate_2

            densacc += ex * g1;                // p_t[lane] for density proxy

            if (lane == 0)
                recs[blockIdx.x * 64 + t] =
                    make_float4(g1n, g2n, __int_as_float(i1),
                                __int_as_float(i2 | (flag << 8)));
        }
        dred[wave][lane] = densacc;
    }
    __syncthreads();
    if (tid < 64) {
        float s = dred[0][tid] + dred[1][tid] + dred[2][tid] + dred[3][tid];
        dens[blockIdx.x * 64 + tid] = s;       // per-block partial, no atomics
    }
}

// ---------------------------------------------------------------------------
// Kernel S: ballot-based parallel rank for position-in-expert.
// 1 block/batch, 1024 threads = 16 waves; lane = token-within-group-of-64.
// (unchanged from R4)
// ---------------------------------------------------------------------------
__global__ __launch_bounds__(1024) void scan_kernel(
    const float4* __restrict__ recs, const float* __restrict__ dens,
    float4* __restrict__ frecs, float* __restrict__ lossp)
{
    const int b = blockIdx.x;
    __shared__ int hist1[32][64], pre1[32][64];
    __shared__ int hist2[32][64], pre2[32][64];
    __shared__ int base2[64];
    __shared__ float dsum[64];

    const int tid = threadIdx.x;
    const int lane = tid & 63;
    const int wave = tid >> 6;

    float4 r[2];
    int e1[2], e2[2], fl[2], rank1[2], rank2[2];
    const unsigned long long below = (1ull << lane) - 1ull;

#pragma unroll
    for (int u = 0; u < 2; ++u) {
        const int g = 2 * wave + u;
        const int tok = g * 64 + lane;
        float4 rr = recs[b * NN + tok];
        r[u] = rr;
        e1[u] = __float_as_int(rr.z);
        int i2f = __float_as_int(rr.w);
        e2[u] = i2f & 63;
        fl[u] = i2f >> 8;

        unsigned long long m = ~0ull, mv = ~0ull;
#pragma unroll
        for (int bit = 0; bit < 6; ++bit) {
            unsigned long long vt = __ballot((e1[u] >> bit) & 1);
            m  &= ((e1[u] >> bit) & 1) ? vt : ~vt;
            mv &= ((lane  >> bit) & 1) ? vt : ~vt;
        }
        rank1[u] = __popcll(m & below);
        hist1[g][lane] = __popcll(mv);

        unsigned long long fv = __ballot(fl[u]);
        m = fv; mv = fv;
#pragma unroll
        for (int bit = 0; bit < 6; ++bit) {
            unsigned long long vt = __ballot((e2[u] >> bit) & 1);
            m  &= ((e2[u] >> bit) & 1) ? vt : ~vt;
            mv &= ((lane  >> bit) & 1) ? vt : ~vt;
        }
        rank2[u] = __popcll(m & below);
        hist2[g][lane] = __popcll(mv);
    }

    if (wave == 0) {  // density sums: 32 gating blocks per batch
        float s = 0.f;
        for (int k = 0; k < 32; ++k) s += dens[(b * 32 + k) * 64 + lane];
        dsum[lane] = s;
    }
    __syncthreads();

    if (wave == 0) {  // cross-group exclusive prefix, lane = expert
        int run = 0;
#pragma unroll
        for (int g = 0; g < 32; ++g) { pre1[g][lane] = run; run += hist1[g][lane]; }
        base2[lane] = run < CAP ? run : CAP;     // mask_1_count = min(count, cap)
        int run2 = 0;
#pragma unroll
        for (int g = 0; g < 32; ++g) { pre2[g][lane] = run2; run2 += hist2[g][lane]; }
        float v = dsum[lane] * (float)run;       // UNCAPPED count for loss
#pragma unroll
        for (int off = 32; off; off >>= 1) v += __shfl_xor(v, off);
        if (lane == 0) lossp[b] = v;
    }
    __syncthreads();

#pragma unroll
    for (int u = 0; u < 2; ++u) {
        const int g = 2 * wave + u;
        const int tok = g * 64 + lane;
        int p1 = rank1[u] + pre1[g][e1[u]];
        int k1 = p1 < CAP;
        int p2 = rank2[u] + pre2[g][e2[u]] + base2[e2[u]];
        int k2 = fl[u] && (p2 < CAP);
        float4 fr;
        fr.x = k1 ? r[u].x : 0.f;
        fr.y = k2 ? r[u].y : 0.f;
        fr.z = __int_as_float(k1 ? (e1[u] * CAP + p1) : -1);
        fr.w = __int_as_float(k2 ? (e2[u] * CAP + p2) : -1);
        frecs[b * NN + tok] = fr;
    }
}

// ---------------------------------------------------------------------------
// Kernel F (v3, unchanged from R4): block = token. Each store instruction is
// 64 lanes x 16 B = 1 KB fully contiguous, regular stores.
// ---------------------------------------------------------------------------
__global__ __launch_bounds__(256) void fill_kernel(
    const float4* __restrict__ frecs, const float* __restrict__ lossp,
    float* __restrict__ out)
{
    const int token = blockIdx.x;
    const int lane = threadIdx.x & 63;
    const int wave = threadIdx.x >> 6;

    const float4 r = frecs[token];       // block-uniform
    const int p1 = __float_as_int(r.z);  // e1*64+pos1 or -1
    const int p2 = __float_as_int(r.w);  // e2*64+pos2 or -1
    const int f1 = p1 >> 2;              // -1 stays -1
    const int f2 = p2 >> 2;
    const int c1 = p1 & 3, c2 = p2 & 3;

    vfloat4* o4 = (vfloat4*)out;
    const size_t slab = (size_t)token << 10;

#pragma unroll
    for (int j = 0; j < 4; ++j) {
        const int f4 = wave * 256 + j * 64 + lane;   // float4 idx within slab
        vfloat4 d = {0.f, 0.f, 0.f, 0.f};
        vfloat4 cv = {0.f, 0.f, 0.f, 0.f};
        const bool h1 = (f1 == f4);
        const bool h2 = (f2 == f4);
#pragma unroll
        for (int jj = 0; jj < 4; ++jj) {
            const bool a1 = h1 && (c1 == jj);
            const bool a2 = h2 && (c2 == jj);
            d[jj]  = (a1 | a2) ? 1.f : 0.f;
            cv[jj] = a1 ? r.x : (a2 ? r.y : 0.f);
        }
        o4[slab + f4] = d;                           // dispatch
        o4[OUT_T_F4 + slab + f4] = cv;               // combine
    }

    if (token == 0 && threadIdx.x == 0) {
        float s = 0.f;
        for (int k = 0; k < 8; ++k) s += lossp[k];
        // loss = sum_b lossp[b] * e^2 / (b*e*n^2) = s / 524288
        out[2 * (size_t)OUT_T_FLOATS] = s * (1.0f / 524288.0f);
    }
}

extern "C" void kernel_launch(void* const* d_in, const int* in_sizes, int n_in,
                              void* d_out, int out_size, void* d_ws, size_t ws_size,
                              hipStream_t stream)
{
    const float* x = (const float*)d_in[0];
    const float* W = (const float*)d_in[1];
    float* out = (float*)d_out;
    char* ws = (char*)d_ws;

    float4* recs  = (float4*)(ws);
    float4* frecs = (float4*)(ws + 262144);
    float*  dens  = (float*)(ws + 524288);
    float*  lossp = (float*)(ws + 589824);

    gating_kernel<<<256, 1024, 0, stream>>>(x, W, recs, dens);
    scan_kernel<<<8, 1024, 0, stream>>>(recs, dens, frecs, lossp);
    fill_kernel<<<16384, 256, 0, stream>>>(frecs, lossp, out);
}

// Round 6
// 612.329 us; speedup vs baseline: 1.3117x; 1.1933x over previous
//
#include <hip/hip_runtime.h>
#include <math.h>

// Problem constants (reference: x[8,2048,1024] f32, W[1024,64] f32)
#define BB 8
#define NN 2048
#define DD 1024
#define EE 64
#define CAP 64
#define NTOK (BB * NN)          // 16384
#define OUT_T_FLOATS 67108864   // 8*2048*64*64 per tensor
#define OUT_T_F4     16777216   // float4 count per tensor

// Workspace layout (bytes):
//   recs      float4[NTOK]   @ 0        {g1n, g2n, bits(i1), bits(i2 | flag<<8)}
//   frecs     float4[NTOK]   @ 262144   {g1|0, g2|0, bits(e1*64+p1 | -1), bits(e2*64+p2 | -1)}
//   dens      float[256*64]  @ 524288   per-gating-block density partials
//   lossp     float[8]       @ 589824   per-batch loss partials

// ---------------------------------------------------------------------------
// Kernel G (v4): spill-proof. 256 blocks x 1024 threads; block owns 64
// tokens (lane = token). 16 waves = 4 k-slices (256 k) x 4 expert-quarters
// (16 experts) -> acc[16] per thread (~60 VGPRs live, no spill), vs
// acc[64] in v2/v3 which likely spilled to scratch inside the FMA loop.
// W addresses wave-uniform; x lane-local. One-shot LDS reduce, both
// phases bank-conflict-free (write stride 1, read stride 65).
// ---------------------------------------------------------------------------
__global__ __launch_bounds__(1024, 4) void gating_kernel(
    const float* __restrict__ x, const float* __restrict__ W,
    float4* __restrict__ recs, float* __restrict__ dens)
{
    __shared__ float red[4][64][65];    // [kslice][expert][token+pad] 65 KB
    __shared__ float dred[4][64];

    const int tid  = threadIdx.x;
    const int lane = tid & 63;                                   // token-in-block
    const int wave = __builtin_amdgcn_readfirstlane(tid >> 6);
    const int ks   = wave & 3;                                   // k-slice (256 k)
    const int eq   = wave >> 2;                                  // expert quarter
    const int tok  = blockIdx.x * 64 + lane;

    float acc[16];
#pragma unroll
    for (int j = 0; j < 16; ++j) acc[j] = 0.f;

    const float4* xq = (const float4*)(x + (size_t)tok * DD + ks * 256);
    const float*  wq = W + (size_t)(ks * 256) * EE + eq * 16;    // wave-uniform

#pragma unroll 2
    for (int c = 0; c < 64; ++c) {           // 64 float4 of x = 256 k
        const float4 xv = xq[c];
        const float xs[4] = {xv.x, xv.y, xv.z, xv.w};
#pragma unroll
        for (int kk = 0; kk < 4; ++kk) {
            const float4* wr = (const float4*)(wq + (size_t)(c * 4 + kk) * EE);
            const float4 w0 = wr[0], w1 = wr[1], w2 = wr[2], w3 = wr[3];
            acc[ 0] = fmaf(xs[kk], w0.x, acc[ 0]);
            acc[ 1] = fmaf(xs[kk], w0.y, acc[ 1]);
            acc[ 2] = fmaf(xs[kk], w0.z, acc[ 2]);
            acc[ 3] = fmaf(xs[kk], w0.w, acc[ 3]);
            acc[ 4] = fmaf(xs[kk], w1.x, acc[ 4]);
            acc[ 5] = fmaf(xs[kk], w1.y, acc[ 5]);
            acc[ 6] = fmaf(xs[kk], w1.z, acc[ 6]);
            acc[ 7] = fmaf(xs[kk], w1.w, acc[ 7]);
            acc[ 8] = fmaf(xs[kk], w2.x, acc[ 8]);
            acc[ 9] = fmaf(xs[kk], w2.y, acc[ 9]);
            acc[10] = fmaf(xs[kk], w2.z, acc[10]);
            acc[11] = fmaf(xs[kk], w2.w, acc[11]);
            acc[12] = fmaf(xs[kk], w3.x, acc[12]);
            acc[13] = fmaf(xs[kk], w3.y, acc[13]);
            acc[14] = fmaf(xs[kk], w3.z, acc[14]);
            acc[15] = fmaf(xs[kk], w3.w, acc[15]);
        }
    }

    // ---- one-shot cross-slice reduce via LDS
#pragma unroll
    for (int j = 0; j < 16; ++j)
        red[ks][eq * 16 + j][lane] = acc[j];     // lane stride 1: conflict-free
    __syncthreads();

    // ---- epilogue: waves 0-3, wave w handles tokens [16w,16w+16); lane = expert
    if (wave < 4) {
        const int t0 = wave * 16;
        float densacc = 0.f;
#pragma unroll 1
        for (int ti = 0; ti < 16; ++ti) {
            const int t = t0 + ti;
            const float lv = ((red[0][lane][t] + red[1][lane][t])
                            + red[2][lane][t]) + red[3][lane][t];  // stride 65: free

            // argmax: value desc, index asc on ties (matches jnp.argmax)
            float v = lv; int bi = lane;
#pragma unroll
            for (int off = 32; off; off >>= 1) {
                float ov = __shfl_xor(v, off);
                int   oi = __shfl_xor(bi, off);
                if (ov > v || (ov == v && oi < bi)) { v = ov; bi = oi; }
            }
            const float m1 = v; const int i1 = bi;
            float v2 = (lane == i1) ? -INFINITY : lv; int b2 = lane;
#pragma unroll
            for (int off = 32; off; off >>= 1) {
                float ov = __shfl_xor(v2, off);
                int   oi = __shfl_xor(b2, off);
                if (ov > v2 || (ov == v2 && oi < b2)) { v2 = ov; b2 = oi; }
            }
            const float m2 = v2; const int i2 = b2;

            float ex = expf(lv - m1);
            float Z = ex;
#pragma unroll
            for (int off = 32; off; off >>= 1) Z += __shfl_xor(Z, off);
            float g1 = 1.0f / Z;               // p[i1]
            float g2 = expf(m2 - m1) * g1;     // p[i2]
            float den = g1 + g2 + 1e-9f;
            float g1n = g1 / den;
            float g2n = g2 / den;
            int flag = (g2n > 0.2f) ? 1 : 0;   // threshold on NORMALIZED gate_2

            densacc += ex * g1;                // p_t[lane] for density proxy

            if (lane == 0)
                recs[blockIdx.x * 64 + t] =
                    make_float4(g1n, g2n, __int_as_float(i1),
                                __int_as_float(i2 | (flag << 8)));
        }
        dred[wave][lane] = densacc;
    }
    __syncthreads();
    if (tid < 64) {
        float s = dred[0][tid] + dred[1][tid] + dred[2][tid] + dred[3][tid];
        dens[blockIdx.x * 64 + tid] = s;       // per-block partial, no atomics
    }
}

// ---------------------------------------------------------------------------
// Kernel S: ballot-based parallel rank for position-in-expert.
// 1 block/batch, 1024 threads = 16 waves (unchanged from R5).
// ---------------------------------------------------------------------------
__global__ __launch_bounds__(1024) void scan_kernel(
    const float4* __restrict__ recs, const float* __restrict__ dens,
    float4* __restrict__ frecs, float* __restrict__ lossp)
{
    const int b = blockIdx.x;
    __shared__ int hist1[32][64], pre1[32][64];
    __shared__ int hist2[32][64], pre2[32][64];
    __shared__ int base2[64];
    __shared__ float dsum[64];

    const int tid = threadIdx.x;
    const int lane = tid & 63;
    const int wave = tid >> 6;

    float4 r[2];
    int e1[2], e2[2], fl[2], rank1[2], rank2[2];
    const unsigned long long below = (1ull << lane) - 1ull;

#pragma unroll
    for (int u = 0; u < 2; ++u) {
        const int g = 2 * wave + u;
        const int tok = g * 64 + lane;
        float4 rr = recs[b * NN + tok];
        r[u] = rr;
        e1[u] = __float_as_int(rr.z);
        int i2f = __float_as_int(rr.w);
        e2[u] = i2f & 63;
        fl[u] = i2f >> 8;

        unsigned long long m = ~0ull, mv = ~0ull;
#pragma unroll
        for (int bit = 0; bit < 6; ++bit) {
            unsigned long long vt = __ballot((e1[u] >> bit) & 1);
            m  &= ((e1[u] >> bit) & 1) ? vt : ~vt;
            mv &= ((lane  >> bit) & 1) ? vt : ~vt;
        }
        rank1[u] = __popcll(m & below);
        hist1[g][lane] = __popcll(mv);

        unsigned long long fv = __ballot(fl[u]);
        m = fv; mv = fv;
#pragma unroll
        for (int bit = 0; bit < 6; ++bit) {
            unsigned long long vt = __ballot((e2[u] >> bit) & 1);
            m  &= ((e2[u] >> bit) & 1) ? vt : ~vt;
            mv &= ((lane  >> bit) & 1) ? vt : ~vt;
        }
        rank2[u] = __popcll(m & below);
        hist2[g][lane] = __popcll(mv);
    }

    if (wave == 0) {  // density sums: 32 gating blocks per batch
        float s = 0.f;
        for (int k = 0; k < 32; ++k) s += dens[(b * 32 + k) * 64 + lane];
        dsum[lane] = s;
    }
    __syncthreads();

    if (wave == 0) {  // cross-group exclusive prefix, lane = expert
        int run = 0;
#pragma unroll
        for (int g = 0; g < 32; ++g) { pre1[g][lane] = run; run += hist1[g][lane]; }
        base2[lane] = run < CAP ? run : CAP;     // mask_1_count = min(count, cap)
        int run2 = 0;
#pragma unroll
        for (int g = 0; g < 32; ++g) { pre2[g][lane] = run2; run2 += hist2[g][lane]; }
        float v = dsum[lane] * (float)run;       // UNCAPPED count for loss
#pragma unroll
        for (int off = 32; off; off >>= 1) v += __shfl_xor(v, off);
        if (lane == 0) lossp[b] = v;
    }
    __syncthreads();

#pragma unroll
    for (int u = 0; u < 2; ++u) {
        const int g = 2 * wave + u;
        const int tok = g * 64 + lane;
        int p1 = rank1[u] + pre1[g][e1[u]];
        int k1 = p1 < CAP;
        int p2 = rank2[u] + pre2[g][e2[u]] + base2[e2[u]];
        int k2 = fl[u] && (p2 < CAP);
        float4 fr;
        fr.x = k1 ? r[u].x : 0.f;
        fr.y = k2 ? r[u].y : 0.f;
        fr.z = __int_as_float(k1 ? (e1[u] * CAP + p1) : -1);
        fr.w = __int_as_float(k2 ? (e2[u] * CAP + p2) : -1);
        frecs[b * NN + tok] = fr;
    }
}

// ---------------------------------------------------------------------------
// Kernel F (v1, verbatim from the best-known R1 total): one float4 of each
// tensor per thread, 64-lane-contiguous stores, regular store path.
// ---------------------------------------------------------------------------
__global__ __launch_bounds__(256) void fill_kernel(
    const float4* __restrict__ frecs, const float* __restrict__ lossp,
    float* __restrict__ out)
{
    const int tid = blockIdx.x * 256 + threadIdx.x;   // 0 .. 16777215
    const int token = tid >> 10;
    const int e  = (tid >> 4) & 63;
    const int c4 = tid & 15;
    float4 r = frecs[token];   // broadcast across 1024 threads -> L1 hit

    float cx = 0.f, cy = 0.f, cz = 0.f, cw = 0.f;
    float dx = 0.f, dy = 0.f, dz = 0.f, dw = 0.f;

    int p1 = __float_as_int(r.z);
    if (p1 >= 0 && (p1 >> 6) == e && ((p1 >> 2) & 15) == c4) {
        int cc = p1 & 3;
        if      (cc == 0) { cx = r.x; dx = 1.f; }
        else if (cc == 1) { cy = r.x; dy = 1.f; }
        else if (cc == 2) { cz = r.x; dz = 1.f; }
        else              { cw = r.x; dw = 1.f; }
    }
    int p2 = __float_as_int(r.w);
    if (p2 >= 0 && (p2 >> 6) == e && ((p2 >> 2) & 15) == c4) {
        int cc = p2 & 3;
        if      (cc == 0) { cx = r.y; dx = 1.f; }
        else if (cc == 1) { cy = r.y; dy = 1.f; }
        else if (cc == 2) { cz = r.y; dz = 1.f; }
        else              { cw = r.y; dw = 1.f; }
    }

    float4* o4 = (float4*)out;
    o4[tid]             = make_float4(dx, dy, dz, dw);   // dispatch
    o4[tid + OUT_T_F4]  = make_float4(cx, cy, cz, cw);   // combine

    if (tid == 0) {
        float s = 0.f;
        for (int k = 0; k < 8; ++k) s += lossp[k];
        // loss = sum_b lossp[b] * e^2 / (b*e*n^2) = s / 524288
        out[2 * (size_t)OUT_T_FLOATS] = s * (1.0f / 524288.0f);
    }
}

extern "C" void kernel_launch(void* const* d_in, const int* in_sizes, int n_in,
                              void* d_out, int out_size, void* d_ws, size_t ws_size,
                              hipStream_t stream)
{
    const float* x = (const float*)d_in[0];
    const float* W = (const float*)d_in[1];
    float* out = (float*)d_out;
    char* ws = (char*)d_ws;

    float4* recs  = (float4*)(ws);
    float4* frecs = (float4*)(ws + 262144);
    float*  dens  = (float*)(ws + 524288);
    float*  lossp = (float*)(ws + 589824);

    gating_kernel<<<256, 1024, 0, stream>>>(x, W, recs, dens);
    scan_kernel<<<8, 1024, 0, stream>>>(recs, dens, frecs, lossp);
    fill_kernel<<<65536, 256, 0, stream>>>(frecs, lossp, out);
}